// Round 7
// baseline (678.101 us; speedup 1.0000x reference)
//
#include <hip/hip_runtime.h>
#include <math.h>

// Instant-NGP hash grid encoder, MI355X. Round 7.
//
// Round-6: 638 us total = ~550 us gathers (16 per-level dispatches, no
// counters visible) + ~88 us transpose (37% occupancy, LDS-capped).
// This round discriminates the gather limiter:
//  - 2 adjacent points/thread -> 16 outstanding gathers (2x MLP), 3x b64
//    x-loads, single b128 nt store. Latency-bound => -30..45% on fine
//    levels; L2-request-rate-bound => unchanged (then: spatial sort next).
//  - transpose half-tile LDS (17.4 KB) -> 8 blocks/CU instead of 4, and
//    transpose drops below fine-gather dur so top-5 exposes gather PMC.

#define LEVELS 16
#define LOG2_T 19
#define TMASK ((1u << LOG2_T) - 1u)

typedef float f32x2 __attribute__((ext_vector_type(2)));
typedef float f32x4 __attribute__((ext_vector_type(4)));

struct ResArgs { float r[LEVELS]; };

__device__ __forceinline__ f32x2 encode_one(
    const f32x2* __restrict__ tbl, float rf,
    float x0, float x1, float x2)
{
    // Same fp32 op chain as the reference.
    const float sx = x0 * rf, sy = x1 * rf, sz = x2 * rf;
    const float px = floorf(sx), py = floorf(sy), pz = floorf(sz);
    const float fx = sx - px, fy = sy - py, fz = sz - pz;
    const unsigned ix = (unsigned)px, iy = (unsigned)py, iz = (unsigned)pz;

    const unsigned hx0 = ix;
    const unsigned hx1 = ix + 1u;
    const unsigned hy0 = iy * 2654435761u;
    const unsigned hy1 = hy0 + 2654435761u;
    const unsigned hz0 = iz * 805459861u;
    const unsigned hz1 = hz0 + 805459861u;

    const unsigned i000 = (hx0 ^ hy0 ^ hz0) & TMASK;
    const unsigned i100 = (hx1 ^ hy0 ^ hz0) & TMASK;
    const unsigned i010 = (hx0 ^ hy1 ^ hz0) & TMASK;
    const unsigned i110 = (hx1 ^ hy1 ^ hz0) & TMASK;
    const unsigned i001 = (hx0 ^ hy0 ^ hz1) & TMASK;
    const unsigned i101 = (hx1 ^ hy0 ^ hz1) & TMASK;
    const unsigned i011 = (hx0 ^ hy1 ^ hz1) & TMASK;
    const unsigned i111 = (hx1 ^ hy1 ^ hz1) & TMASK;

    const f32x2 c000 = tbl[i000];
    const f32x2 c100 = tbl[i100];
    const f32x2 c010 = tbl[i010];
    const f32x2 c110 = tbl[i110];
    const f32x2 c001 = tbl[i001];
    const f32x2 c101 = tbl[i101];
    const f32x2 c011 = tbl[i011];
    const f32x2 c111 = tbl[i111];

    const float wx1 = fx, wx0 = 1.0f - fx;
    const float wy1 = fy, wy0 = 1.0f - fy;
    const float wz1 = fz, wz0 = 1.0f - fz;
    const float w00 = wy0 * wz0;
    const float w10 = wy1 * wz0;
    const float w01 = wy0 * wz1;
    const float w11 = wy1 * wz1;

    float w, a0, a1;
    w = wx0 * w00; a0 = w * c000.x;          a1 = w * c000.y;
    w = wx1 * w00; a0 = fmaf(w, c100.x, a0); a1 = fmaf(w, c100.y, a1);
    w = wx0 * w10; a0 = fmaf(w, c010.x, a0); a1 = fmaf(w, c010.y, a1);
    w = wx1 * w10; a0 = fmaf(w, c110.x, a0); a1 = fmaf(w, c110.y, a1);
    w = wx0 * w01; a0 = fmaf(w, c001.x, a0); a1 = fmaf(w, c001.y, a1);
    w = wx1 * w01; a0 = fmaf(w, c101.x, a0); a1 = fmaf(w, c101.y, a1);
    w = wx0 * w11; a0 = fmaf(w, c011.x, a0); a1 = fmaf(w, c011.y, a1);
    w = wx1 * w11; a0 = fmaf(w, c111.x, a0); a1 = fmaf(w, c111.y, a1);

    f32x2 o; o.x = a0; o.y = a1;
    return o;
}

// ---- Per-level gather, 2 adjacent points/thread (16 in-flight gathers) --
__global__ __launch_bounds__(256) void ngp_gather_level2(
    const float* __restrict__ x,
    const float* __restrict__ table,
    f32x2* __restrict__ out_t,     // [LEVELS][n] scratch
    float rf, int level, unsigned n)   // host guarantees n % 512 == 0
{
    const unsigned gid = blockIdx.x * 256u + threadIdx.x;   // pair index
    const unsigned p0 = 2u * gid;
    if (p0 >= n) return;

    // 6 floats (two points) via 3 b64 nt loads; nt keeps the 4 MB table
    // slice resident in the XCD L2.
    const f32x2* __restrict__ xv = (const f32x2*)x;
    const f32x2 u0 = __builtin_nontemporal_load(&xv[3u*gid]);
    const f32x2 u1 = __builtin_nontemporal_load(&xv[3u*gid+1u]);
    const f32x2 u2 = __builtin_nontemporal_load(&xv[3u*gid+2u]);

    const f32x2* __restrict__ tbl =
        (const f32x2*)table + ((size_t)level << LOG2_T);

    // Two independent encodes -> compiler hoists all 16 gathers together.
    const f32x2 oa = encode_one(tbl, rf, u0.x, u0.y, u1.x);
    const f32x2 ob = encode_one(tbl, rf, u1.y, u2.x, u2.y);

    f32x4 v; v.x = oa.x; v.y = oa.y; v.z = ob.x; v.w = ob.y;
    // lane-contiguous 1 KB/wave per instruction -> nt safe.
    __builtin_nontemporal_store(v, (f32x4*)&out_t[(size_t)level * n + p0]);
}

// ---- LDS transpose [L][N] -> [N][L], half-tiles of 128 points ----------
// LDS 17408 B -> 8 blocks/CU (round-6 was 34 KB -> 4 blocks, 37% occ).
__global__ __launch_bounds__(256) void ngp_transpose_lds(
    const f32x2* __restrict__ out_t,
    f32x4* __restrict__ out,       // [n*8] f32x4
    unsigned n)                    // host guarantees n % 256 == 0
{
    __shared__ f32x2 lds[128][LEVELS + 1];   // +1 pad: 2-way banking = free
    const unsigned t = threadIdx.x;
    const unsigned pbase = blockIdx.x * 256u;

    #pragma unroll
    for (int half = 0; half < 2; ++half) {
        const unsigned p0 = pbase + (unsigned)half * 128u;
        // Load 128 pts x 16 levels = 2048 f32x2 (256 thr x 8); each wave
        // reads 512 B contiguous within one level row.
        #pragma unroll
        for (int j = 0; j < 8; ++j) {
            const unsigned idx = (unsigned)j * 256u + t;  // 0..2047
            const unsigned l  = idx >> 7;                 // wave-uniform
            const unsigned pp = idx & 127u;
            lds[pp][l] = out_t[(size_t)l * n + p0 + pp];
        }
        __syncthreads();
        // Store 128 pts x 8 f32x4 (256 thr x 4); 1 KB/wave contiguous, nt.
        #pragma unroll
        for (int j = 0; j < 4; ++j) {
            const unsigned g = (unsigned)j * 256u + t;    // 0..1023
            const unsigned p = g >> 3, q = g & 7u;
            const f32x2 a = lds[p][2u*q];
            const f32x2 b = lds[p][2u*q + 1u];
            f32x4 v; v.x = a.x; v.y = a.y; v.z = b.x; v.w = b.y;
            __builtin_nontemporal_store(v, &out[(size_t)p0 * 8u + g]);
        }
        __syncthreads();
    }
}

// ---- Fallback (round-3 proven): direct point-major ----------------------
__global__ __launch_bounds__(256) void ngp_encode_direct(
    const float* __restrict__ x,
    const float* __restrict__ table,
    f32x2* __restrict__ out,
    ResArgs res,
    unsigned n_points)
{
    const unsigned t = blockIdx.x * 256u + threadIdx.x;
    const unsigned level = t & (LEVELS - 1u);
    const unsigned p = t >> 4;
    if (p >= n_points) return;
    const float x0 = x[3u*p], x1 = x[3u*p+1u], x2 = x[3u*p+2u];
    const f32x2* __restrict__ tbl =
        (const f32x2*)table + ((size_t)level << LOG2_T);
    f32x2 o = encode_one(tbl, res.r[level], x0, x1, x2);
    __builtin_nontemporal_store(o, &out[t]);
}

extern "C" void kernel_launch(void* const* d_in, const int* in_sizes, int n_in,
                              void* d_out, int out_size, void* d_ws, size_t ws_size,
                              hipStream_t stream) {
    const float* x     = (const float*)d_in[0];
    const float* table = (const float*)d_in[1];
    const unsigned n_points = (unsigned)(in_sizes[0] / 3);

    // numpy RES replication (same host libm).
    ResArgs res;
    const double scale = exp((log(512.0) - log(16.0)) / 15.0);
    for (int l = 0; l < LEVELS; ++l) {
        res.r[l] = (float)floor(16.0 * pow(scale, (double)l));
    }

    const size_t scratch_needed = (size_t)LEVELS * n_points * sizeof(f32x2);
    const bool fits = (ws_size >= scratch_needed) && (n_points % 512u == 0u);

    if (fits) {
        f32x2* out_t = (f32x2*)d_ws;
        const unsigned gblk = n_points / 512u;   // 2 pts/thread
        for (int l = 0; l < LEVELS; ++l) {
            ngp_gather_level2<<<dim3(gblk), dim3(256), 0, stream>>>(
                x, table, out_t, res.r[l], l, n_points);
        }
        const unsigned tblk = n_points / 256u;
        ngp_transpose_lds<<<dim3(tblk), dim3(256), 0, stream>>>(
            out_t, (f32x4*)d_out, n_points);
    } else {
        const unsigned total = n_points * LEVELS;
        const unsigned nblk = (total + 255u) / 256u;
        ngp_encode_direct<<<dim3(nblk), dim3(256), 0, stream>>>(
            x, table, (f32x2*)d_out, res, n_points);
    }
}